// Round 5
// baseline (526.506 us; speedup 1.0000x reference)
//
#include <hip/hip_runtime.h>

typedef __attribute__((ext_vector_type(8))) short s16x8;
typedef __attribute__((ext_vector_type(4))) float f32x4;

#define LN_EPS 1e-5f

__device__ __forceinline__ unsigned short f2bf(float f) {
  unsigned int u = __float_as_uint(f);
  u += 0x7fffu + ((u >> 16) & 1u);
  return (unsigned short)(u >> 16);
}

__device__ __forceinline__ unsigned cvt_pk_bf16(float lo, float hi) {
  unsigned r;
  asm("v_cvt_pk_bf16_f32 %0, %1, %2" : "=v"(r) : "v"(lo), "v"(hi));
  return r;
}

// tanh-approx GELU: max abs err vs exact ~1e-3.
__device__ __forceinline__ float gelu_fast(float x) {
  float x2 = x * x;
  float y = x * (0.7978845608f + 0.03567740814f * x2);
  float t = __expf(-2.0f * fabsf(y));
  float th = (1.0f - t) / (1.0f + t);
  th = copysignf(th, y);
  return 0.5f * x * (1.0f + th);
}

// ws layout (ushort elems), fragment-major, N-sliced per wave w (frag = 64 lanes x 8 bf16 = 1KB):
//   ws1 [0, 65536)      : GEMM1, frag f = (w*8+kk)*2+nf  (w 0..7, kk 0..7, nf 0..1), n = w*32+nf*16+l15
//   ws2 [65536, 98304)  : GEMM2, frag f = w*8+kk,  n = w*16+l15
//   ws3 [98304, 114688) : GEMM3, frag f = w*4+kk (kk 0..3), n = w*16+l15
//   [114688, 114944)    : 128 f32 = Wm[128,:] (importance row)
__global__ void prep_weights(const float* __restrict__ W1, const float* __restrict__ W2,
                             const float* __restrict__ Wm, unsigned short* __restrict__ ws) {
  int i = blockIdx.x * 256 + threadIdx.x;
  if (i < 65536) {
    int f = i >> 9, lane = (i >> 3) & 63, j = i & 7;
    int w = f >> 4, kk = (f >> 1) & 7, nf = f & 1;
    int n = w * 32 + nf * 16 + (lane & 15);
    int k = kk * 32 + (lane >> 4) * 8 + j;
    ws[i] = f2bf(W1[k * 256 + n]);
  } else if (i < 98304) {
    int t = i - 65536;
    int f = t >> 9, lane = (t >> 3) & 63, j = t & 7;
    int w = f >> 3, kk = f & 7;
    int n = w * 16 + (lane & 15);
    int k = kk * 32 + (lane >> 4) * 8 + j;
    ws[i] = f2bf(W2[k * 128 + n]);
  } else if (i < 114688) {
    int t = i - 98304;
    int f = t >> 9, lane = (t >> 3) & 63, j = t & 7;
    int w = f >> 2, kk = f & 3;
    int n = w * 16 + (lane & 15);
    int k = kk * 32 + (lane >> 4) * 8 + j;
    ws[i] = f2bf(Wm[k * 128 + n]);
  } else if (i < 114944) {
    int c = i - 114688;
    reinterpret_cast<float*>(ws + 114688)[c] = Wm[128 * 128 + c];
  }
}

// 8 waves/block, 64 rows/block. Waves split N; weights read ONCE per block (4x L2 cut).
// A / H1 / H2 time-multiplex one 32KB LDS buffer (barrier-separated).
__global__ __launch_bounds__(512, 4) void fused_edge_group(
    const float* __restrict__ emb, const int* __restrict__ eg,
    const float* __restrict__ imp,
    const float* __restrict__ b1, const float* __restrict__ g1, const float* __restrict__ be1,
    const float* __restrict__ b2, const float* __restrict__ g2, const float* __restrict__ be2,
    const float* __restrict__ bm,
    const unsigned short* __restrict__ ws,
    float* __restrict__ out, int G) {

  __shared__ __align__(16) unsigned short sh[64 * 256];  // 32KB: A -> H1 -> H2
  __shared__ float st[2][8][64];                          // cross-wave LN partials
  __shared__ float murs[2][64];                           // mu, rsqrt per row

  const int tid = threadIdx.x;
  const int lane = tid & 63;
  const int w = tid >> 6;        // 0..7
  const int l15 = lane & 15;
  const int lgrp = lane >> 4;    // 0..3
  const int g0 = blockIdx.x * 64;

  // ---- gather: 64 rows x 512B f32 -> bf16 into sh (A layout, swizzled) ----
  #pragma unroll
  for (int it = 0; it < 4; ++it) {
    int s = tid + it * 512;          // 0..2047 : 16B bf16 slots of [64][512B]
    int row = s >> 5, sc = s & 31;
    int g = g0 + row; if (g >= G) g = G - 1;
    int idx = eg[2 * g + (sc >> 4)];
    const float4* p = reinterpret_cast<const float4*>(emb + (size_t)idx * 128 + (sc & 15) * 8);
    float4 va = p[0], vb = p[1];
    uint4 v;
    v.x = cvt_pk_bf16(va.x, va.y); v.y = cvt_pk_bf16(va.z, va.w);
    v.z = cvt_pk_bf16(vb.x, vb.y); v.w = cvt_pk_bf16(vb.z, vb.w);
    int byte = (row * 512 + sc * 16) ^ ((row & 7) << 4);
    *reinterpret_cast<uint4*>(reinterpret_cast<char*>(sh) + byte) = v;
  }
  __syncthreads();

  const int sw = (l15 & 7) << 4;   // A-read swizzle (row = mt*16+l15)

  // ---- GEMM1: all 64 rows x 32-col slice [w*32, w*32+32) ----
  f32x4 acc[4][2];
  #pragma unroll
  for (int mt = 0; mt < 4; ++mt) {
    acc[mt][0] = (f32x4){0.f, 0.f, 0.f, 0.f};
    acc[mt][1] = (f32x4){0.f, 0.f, 0.f, 0.f};
  }
  {
    const unsigned short* ws1w = ws + w * (16 * 512);
    s16x8 bD[2][2];
    bD[0][0] = *reinterpret_cast<const s16x8*>(ws1w + 0 * 512 + lane * 8);
    bD[0][1] = *reinterpret_cast<const s16x8*>(ws1w + 1 * 512 + lane * 8);
    #pragma unroll
    for (int kk = 0; kk < 8; ++kk) {
      if (kk < 7) {
        bD[(kk + 1) & 1][0] = *reinterpret_cast<const s16x8*>(ws1w + ((kk + 1) * 2 + 0) * 512 + lane * 8);
        bD[(kk + 1) & 1][1] = *reinterpret_cast<const s16x8*>(ws1w + ((kk + 1) * 2 + 1) * 512 + lane * 8);
      }
      #pragma unroll
      for (int mt = 0; mt < 4; ++mt) {
        int abyte = ((mt * 16 + l15) * 512 + kk * 64 + lgrp * 16) ^ sw;
        s16x8 af = *reinterpret_cast<const s16x8*>(reinterpret_cast<const char*>(sh) + abyte);
        acc[mt][0] = __builtin_amdgcn_mfma_f32_16x16x32_bf16(af, bD[kk & 1][0], acc[mt][0], 0, 0, 0);
        acc[mt][1] = __builtin_amdgcn_mfma_f32_16x16x32_bf16(af, bD[kk & 1][1], acc[mt][1], 0, 0, 0);
      }
    }
  }

  // ---- epilogue1: bias+GELU, per-row partial stats over the 32-col slice ----
  float sA[4][4], qA[4][4];
  {
    float b1v0 = b1[w * 32 + l15], b1v1 = b1[w * 32 + 16 + l15];
    #pragma unroll
    for (int mt = 0; mt < 4; ++mt)
      #pragma unroll
      for (int r = 0; r < 4; ++r) {
        float x0 = gelu_fast(acc[mt][0][r] + b1v0);
        float x1 = gelu_fast(acc[mt][1][r] + b1v1);
        acc[mt][0][r] = x0; acc[mt][1][r] = x1;
        sA[mt][r] = x0 + x1; qA[mt][r] = x0 * x0 + x1 * x1;
      }
    #pragma unroll
    for (int m = 1; m < 16; m <<= 1)
      #pragma unroll
      for (int mt = 0; mt < 4; ++mt)
        #pragma unroll
        for (int r = 0; r < 4; ++r) {
          sA[mt][r] += __shfl_xor(sA[mt][r], m);
          qA[mt][r] += __shfl_xor(qA[mt][r], m);
        }
    if (l15 == 0) {
      #pragma unroll
      for (int mt = 0; mt < 4; ++mt)
        #pragma unroll
        for (int r = 0; r < 4; ++r) {
          int row = mt * 16 + lgrp * 4 + r;
          st[0][w][row] = sA[mt][r]; st[1][w][row] = qA[mt][r];
        }
    }
  }
  __syncthreads();
  if (tid < 64) {
    float ms = 0.f, mq = 0.f;
    #pragma unroll
    for (int w2 = 0; w2 < 8; ++w2) { ms += st[0][w2][tid]; mq += st[1][w2][tid]; }
    float mu = ms * (1.f / 256.f);
    float var = mq * (1.f / 256.f) - mu * mu;
    murs[0][tid] = mu; murs[1][tid] = rsqrtf(var + LN_EPS);
  }
  __syncthreads();
  // normalize slice -> H1 (same 32KB buffer; all GEMM1 A-reads done before barrier)
  {
    float g1v0 = g1[w * 32 + l15], g1v1 = g1[w * 32 + 16 + l15];
    float be1v0 = be1[w * 32 + l15], be1v1 = be1[w * 32 + 16 + l15];
    #pragma unroll
    for (int mt = 0; mt < 4; ++mt)
      #pragma unroll
      for (int r = 0; r < 4; ++r) {
        int row = mt * 16 + lgrp * 4 + r;
        float mu = murs[0][row], rs = murs[1][row];
        float y0 = (acc[mt][0][r] - mu) * rs * g1v0 + be1v0;
        float y1 = (acc[mt][1][r] - mu) * rs * g1v1 + be1v1;
        int base = row * 512, rsw = (row & 7) << 4;
        int c0 = (w * 32 + l15) * 2, c1 = c0 + 32;
        *reinterpret_cast<unsigned short*>(reinterpret_cast<char*>(sh) + ((base + c0) ^ rsw)) =
            (unsigned short)cvt_pk_bf16(y0, y0);
        *reinterpret_cast<unsigned short*>(reinterpret_cast<char*>(sh) + ((base + c1) ^ rsw)) =
            (unsigned short)cvt_pk_bf16(y1, y1);
      }
  }
  __syncthreads();

  // ---- GEMM2: all 64 rows x 16-col slice [w*16, +16) ----
  f32x4 acc2[4];
  #pragma unroll
  for (int mt = 0; mt < 4; ++mt) acc2[mt] = (f32x4){0.f, 0.f, 0.f, 0.f};
  {
    const unsigned short* ws2w = ws + 65536 + w * (8 * 512);
    s16x8 bD[2];
    bD[0] = *reinterpret_cast<const s16x8*>(ws2w + lane * 8);
    #pragma unroll
    for (int kk = 0; kk < 8; ++kk) {
      if (kk < 7)
        bD[(kk + 1) & 1] = *reinterpret_cast<const s16x8*>(ws2w + (kk + 1) * 512 + lane * 8);
      #pragma unroll
      for (int mt = 0; mt < 4; ++mt) {
        int abyte = ((mt * 16 + l15) * 512 + kk * 64 + lgrp * 16) ^ sw;
        s16x8 af = *reinterpret_cast<const s16x8*>(reinterpret_cast<const char*>(sh) + abyte);
        acc2[mt] = __builtin_amdgcn_mfma_f32_16x16x32_bf16(af, bD[kk & 1], acc2[mt], 0, 0, 0);
      }
    }
  }

  // ---- epilogue2: bias+ReLU, stats over 16-col slice ----
  {
    float b2v = b2[w * 16 + l15];
    #pragma unroll
    for (int mt = 0; mt < 4; ++mt)
      #pragma unroll
      for (int r = 0; r < 4; ++r) {
        float x = fmaxf(acc2[mt][r] + b2v, 0.f);
        acc2[mt][r] = x;
        sA[mt][r] = x; qA[mt][r] = x * x;
      }
    #pragma unroll
    for (int m = 1; m < 16; m <<= 1)
      #pragma unroll
      for (int mt = 0; mt < 4; ++mt)
        #pragma unroll
        for (int r = 0; r < 4; ++r) {
          sA[mt][r] += __shfl_xor(sA[mt][r], m);
          qA[mt][r] += __shfl_xor(qA[mt][r], m);
        }
    if (l15 == 0) {
      #pragma unroll
      for (int mt = 0; mt < 4; ++mt)
        #pragma unroll
        for (int r = 0; r < 4; ++r) {
          int row = mt * 16 + lgrp * 4 + r;
          st[0][w][row] = sA[mt][r]; st[1][w][row] = qA[mt][r];
        }
    }
  }
  __syncthreads();
  if (tid < 64) {
    float ms = 0.f, mq = 0.f;
    #pragma unroll
    for (int w2 = 0; w2 < 8; ++w2) { ms += st[0][w2][tid]; mq += st[1][w2][tid]; }
    float mu = ms * (1.f / 128.f);
    float var = mq * (1.f / 128.f) - mu * mu;
    murs[0][tid] = mu; murs[1][tid] = rsqrtf(var + LN_EPS);
  }
  __syncthreads();
  // normalize slice -> H2 (row stride 256B, same buffer; H1 reads all done)
  {
    float g2v = g2[w * 16 + l15], be2v = be2[w * 16 + l15];
    #pragma unroll
    for (int mt = 0; mt < 4; ++mt)
      #pragma unroll
      for (int r = 0; r < 4; ++r) {
        int row = mt * 16 + lgrp * 4 + r;
        float mu = murs[0][row], rs = murs[1][row];
        float y = (acc2[mt][r] - mu) * rs * g2v + be2v;
        int byte = (row * 256 + (w * 16 + l15) * 2) ^ ((row & 7) << 4);
        *reinterpret_cast<unsigned short*>(reinterpret_cast<char*>(sh) + byte) =
            (unsigned short)cvt_pk_bf16(y, y);
      }
  }
  __syncthreads();

  // ---- GEMM3: all 64 rows x 16-col slice ----
  f32x4 acc3[4];
  #pragma unroll
  for (int mt = 0; mt < 4; ++mt) acc3[mt] = (f32x4){0.f, 0.f, 0.f, 0.f};
  {
    const unsigned short* ws3w = ws + 98304 + w * (4 * 512);
    s16x8 bD[2];
    bD[0] = *reinterpret_cast<const s16x8*>(ws3w + lane * 8);
    #pragma unroll
    for (int kk = 0; kk < 4; ++kk) {
      if (kk < 3)
        bD[(kk + 1) & 1] = *reinterpret_cast<const s16x8*>(ws3w + (kk + 1) * 512 + lane * 8);
      #pragma unroll
      for (int mt = 0; mt < 4; ++mt) {
        int abyte = ((mt * 16 + l15) * 256 + kk * 64 + lgrp * 16) ^ sw;
        s16x8 af = *reinterpret_cast<const s16x8*>(reinterpret_cast<const char*>(sh) + abyte);
        acc3[mt] = __builtin_amdgcn_mfma_f32_16x16x32_bf16(af, bD[kk & 1], acc3[mt], 0, 0, 0);
      }
    }
  }

  // ---- epilogue3: + bm + imp*Wm[128,:], ReLU, store ----
  {
    int col = w * 16 + l15;
    float bmv = bm[col];
    float wlv = reinterpret_cast<const float*>(ws + 114688)[col];
    #pragma unroll
    for (int mt = 0; mt < 4; ++mt)
      #pragma unroll
      for (int r = 0; r < 4; ++r) {
        int row = mt * 16 + lgrp * 4 + r;
        int g = g0 + row;
        if (g < G) {
          float y = acc3[mt][r] + bmv + imp[g] * wlv;
          out[(size_t)g * 128 + col] = fmaxf(y, 0.f);
        }
      }
  }
}

extern "C" void kernel_launch(void* const* d_in, const int* in_sizes, int n_in,
                              void* d_out, int out_size, void* d_ws, size_t ws_size,
                              hipStream_t stream) {
  const float* emb = (const float*)d_in[0];
  const int* eg    = (const int*)d_in[1];
  const float* imp = (const float*)d_in[2];
  const float* W1  = (const float*)d_in[3];
  const float* b1  = (const float*)d_in[4];
  const float* g1  = (const float*)d_in[5];
  const float* be1 = (const float*)d_in[6];
  const float* W2  = (const float*)d_in[7];
  const float* b2  = (const float*)d_in[8];
  const float* g2  = (const float*)d_in[9];
  const float* be2 = (const float*)d_in[10];
  const float* Wm  = (const float*)d_in[11];
  const float* bm  = (const float*)d_in[12];
  unsigned short* ws = (unsigned short*)d_ws;
  float* out = (float*)d_out;
  int G = in_sizes[2];

  prep_weights<<<(114944 + 255) / 256, 256, 0, stream>>>(W1, W2, Wm, ws);
  int nblk = (G + 63) / 64;
  fused_edge_group<<<nblk, 512, 0, stream>>>(emb, eg, imp, b1, g1, be1, b2, g2, be2, bm,
                                             ws, out, G);
}

// Round 6
// 337.122 us; speedup vs baseline: 1.5618x; 1.5618x over previous
//
#include <hip/hip_runtime.h>

typedef __attribute__((ext_vector_type(8))) short s16x8;
typedef __attribute__((ext_vector_type(4))) float f32x4;

#define LN_EPS 1e-5f

__device__ __forceinline__ unsigned short f2bf(float f) {
  unsigned int u = __float_as_uint(f);
  u += 0x7fffu + ((u >> 16) & 1u);
  return (unsigned short)(u >> 16);
}

__device__ __forceinline__ unsigned cvt_pk_bf16(float lo, float hi) {
  unsigned r;
  asm("v_cvt_pk_bf16_f32 %0, %1, %2" : "=v"(r) : "v"(lo), "v"(hi));
  return r;
}

// tanh-approx GELU: max abs err vs exact ~1e-3.
__device__ __forceinline__ float gelu_fast(float x) {
  float x2 = x * x;
  float y = x * (0.7978845608f + 0.03567740814f * x2);
  float t = __expf(-2.0f * fabsf(y));
  float th = (1.0f - t) / (1.0f + t);
  th = copysignf(th, y);
  return 0.5f * x * (1.0f + th);
}

// ws layout (ushort elems), fragment-major, N-sliced per wave w (frag = 64 lanes x 8 bf16 = 1KB):
//   ws1 [0, 65536)      : GEMM1, frag f = (w*8+kk)*2+nf  (w 0..7, kk 0..7, nf 0..1), n = w*32+nf*16+l15
//   ws2 [65536, 98304)  : GEMM2, frag f = w*8+kk,  n = w*16+l15
//   ws3 [98304, 114688) : GEMM3, frag f = w*4+kk (kk 0..3), n = w*16+l15
//   [114688, 114944)    : 128 f32 = Wm[128,:] (importance row)
__global__ void prep_weights(const float* __restrict__ W1, const float* __restrict__ W2,
                             const float* __restrict__ Wm, unsigned short* __restrict__ ws) {
  int i = blockIdx.x * 256 + threadIdx.x;
  if (i < 65536) {
    int f = i >> 9, lane = (i >> 3) & 63, j = i & 7;
    int w = f >> 4, kk = (f >> 1) & 7, nf = f & 1;
    int n = w * 32 + nf * 16 + (lane & 15);
    int k = kk * 32 + (lane >> 4) * 8 + j;
    ws[i] = f2bf(W1[k * 256 + n]);
  } else if (i < 98304) {
    int t = i - 65536;
    int f = t >> 9, lane = (t >> 3) & 63, j = t & 7;
    int w = f >> 3, kk = f & 7;
    int n = w * 16 + (lane & 15);
    int k = kk * 32 + (lane >> 4) * 8 + j;
    ws[i] = f2bf(W2[k * 128 + n]);
  } else if (i < 114688) {
    int t = i - 98304;
    int f = t >> 9, lane = (t >> 3) & 63, j = t & 7;
    int w = f >> 2, kk = f & 3;
    int n = w * 16 + (lane & 15);
    int k = kk * 32 + (lane >> 4) * 8 + j;
    ws[i] = f2bf(Wm[k * 128 + n]);
  } else if (i < 114944) {
    int c = i - 114688;
    reinterpret_cast<float*>(ws + 114688)[c] = Wm[128 * 128 + c];
  }
}

// 8 waves/block, 64 rows/block. Waves split N; weights read ONCE per block.
// Padded row strides (A/H1: 520B, H2: 264B) -> bank-balanced reads, spread writes.
// launch_bounds(512,2): empirically VGPR cap = 256/arg2 = 128 (R2-R5 law) -> no spill.
__global__ __launch_bounds__(512, 2) void fused_edge_group(
    const float* __restrict__ emb, const int* __restrict__ eg,
    const float* __restrict__ imp,
    const float* __restrict__ b1, const float* __restrict__ g1, const float* __restrict__ be1,
    const float* __restrict__ b2, const float* __restrict__ g2, const float* __restrict__ be2,
    const float* __restrict__ bm,
    const unsigned short* __restrict__ ws,
    float* __restrict__ out, int G) {

  __shared__ __align__(16) char sh[64 * 520];   // 33280B: A -> H1 (520B rows) -> H2 (264B rows)
  __shared__ float st[2][8][64];                 // cross-wave LN partials
  __shared__ float murs[2][64];                  // mu, rsqrt per row

  const int tid = threadIdx.x;
  const int lane = tid & 63;
  const int w = tid >> 6;        // 0..7
  const int l15 = lane & 15;
  const int lgrp = lane >> 4;    // 0..3
  const int g0 = blockIdx.x * 64;

  // ---- gather: 64 rows x 512B f32 -> bf16 into sh rows of 520B ----
  #pragma unroll
  for (int it = 0; it < 4; ++it) {
    int s = tid + it * 512;          // 0..2047 : 16B bf16 slots of [64][512B payload]
    int row = s >> 5, sc = s & 31;
    int g = g0 + row; if (g >= G) g = G - 1;
    int idx = eg[2 * g + (sc >> 4)];
    const float4* p = reinterpret_cast<const float4*>(emb + (size_t)idx * 128 + (sc & 15) * 8);
    float4 va = p[0], vb = p[1];
    uint4 v;
    v.x = cvt_pk_bf16(va.x, va.y); v.y = cvt_pk_bf16(va.z, va.w);
    v.z = cvt_pk_bf16(vb.x, vb.y); v.w = cvt_pk_bf16(vb.z, vb.w);
    *reinterpret_cast<uint4*>(sh + row * 520 + sc * 16) = v;
  }
  __syncthreads();

  // ---- GEMM1: all 64 rows x 32-col slice [w*32, w*32+32) ----
  f32x4 acc[4][2];
  #pragma unroll
  for (int mt = 0; mt < 4; ++mt) {
    acc[mt][0] = (f32x4){0.f, 0.f, 0.f, 0.f};
    acc[mt][1] = (f32x4){0.f, 0.f, 0.f, 0.f};
  }
  {
    const unsigned short* ws1w = ws + w * (16 * 512);
    s16x8 bD[2][2];
    bD[0][0] = *reinterpret_cast<const s16x8*>(ws1w + 0 * 512 + lane * 8);
    bD[0][1] = *reinterpret_cast<const s16x8*>(ws1w + 1 * 512 + lane * 8);
    #pragma unroll
    for (int kk = 0; kk < 8; ++kk) {
      if (kk < 7) {
        bD[(kk + 1) & 1][0] = *reinterpret_cast<const s16x8*>(ws1w + ((kk + 1) * 2 + 0) * 512 + lane * 8);
        bD[(kk + 1) & 1][1] = *reinterpret_cast<const s16x8*>(ws1w + ((kk + 1) * 2 + 1) * 512 + lane * 8);
      }
      #pragma unroll
      for (int mt = 0; mt < 4; ++mt) {
        s16x8 af = *reinterpret_cast<const s16x8*>(sh + (mt * 16 + l15) * 520 + kk * 64 + lgrp * 16);
        acc[mt][0] = __builtin_amdgcn_mfma_f32_16x16x32_bf16(af, bD[kk & 1][0], acc[mt][0], 0, 0, 0);
        acc[mt][1] = __builtin_amdgcn_mfma_f32_16x16x32_bf16(af, bD[kk & 1][1], acc[mt][1], 0, 0, 0);
      }
    }
  }

  // ---- epilogue1: bias+GELU, per-mt stats reduce (small live set) ----
  {
    float b1v0 = b1[w * 32 + l15], b1v1 = b1[w * 32 + 16 + l15];
    #pragma unroll
    for (int mt = 0; mt < 4; ++mt) {
      float sr[4], qr[4];
      #pragma unroll
      for (int r = 0; r < 4; ++r) {
        float x0 = gelu_fast(acc[mt][0][r] + b1v0);
        float x1 = gelu_fast(acc[mt][1][r] + b1v1);
        acc[mt][0][r] = x0; acc[mt][1][r] = x1;
        sr[r] = x0 + x1; qr[r] = x0 * x0 + x1 * x1;
      }
      #pragma unroll
      for (int m = 1; m < 16; m <<= 1)
        #pragma unroll
        for (int r = 0; r < 4; ++r) {
          sr[r] += __shfl_xor(sr[r], m);
          qr[r] += __shfl_xor(qr[r], m);
        }
      if (l15 == 0) {
        #pragma unroll
        for (int r = 0; r < 4; ++r) {
          int row = mt * 16 + lgrp * 4 + r;
          st[0][w][row] = sr[r]; st[1][w][row] = qr[r];
        }
      }
    }
  }
  __syncthreads();
  if (tid < 64) {
    float ms = 0.f, mq = 0.f;
    #pragma unroll
    for (int w2 = 0; w2 < 8; ++w2) { ms += st[0][w2][tid]; mq += st[1][w2][tid]; }
    float mu = ms * (1.f / 256.f);
    float var = mq * (1.f / 256.f) - mu * mu;
    murs[0][tid] = mu; murs[1][tid] = rsqrtf(var + LN_EPS);
  }
  __syncthreads();
  // normalize slice -> H1 (520B rows; A fully consumed)
  {
    float g1v0 = g1[w * 32 + l15], g1v1 = g1[w * 32 + 16 + l15];
    float be1v0 = be1[w * 32 + l15], be1v1 = be1[w * 32 + 16 + l15];
    #pragma unroll
    for (int mt = 0; mt < 4; ++mt)
      #pragma unroll
      for (int r = 0; r < 4; ++r) {
        int row = mt * 16 + lgrp * 4 + r;
        float mu = murs[0][row], rs = murs[1][row];
        float y0 = (acc[mt][0][r] - mu) * rs * g1v0 + be1v0;
        float y1 = (acc[mt][1][r] - mu) * rs * g1v1 + be1v1;
        char* rp = sh + row * 520 + (w * 32 + l15) * 2;
        *reinterpret_cast<unsigned short*>(rp) = f2bf(y0);
        *reinterpret_cast<unsigned short*>(rp + 32) = f2bf(y1);
      }
  }
  __syncthreads();

  // ---- GEMM2: all 64 rows x 16-col slice [w*16, +16) ----
  f32x4 acc2[4];
  #pragma unroll
  for (int mt = 0; mt < 4; ++mt) acc2[mt] = (f32x4){0.f, 0.f, 0.f, 0.f};
  {
    const unsigned short* ws2w = ws + 65536 + w * (8 * 512);
    s16x8 bD[2];
    bD[0] = *reinterpret_cast<const s16x8*>(ws2w + lane * 8);
    #pragma unroll
    for (int kk = 0; kk < 8; ++kk) {
      if (kk < 7)
        bD[(kk + 1) & 1] = *reinterpret_cast<const s16x8*>(ws2w + (kk + 1) * 512 + lane * 8);
      #pragma unroll
      for (int mt = 0; mt < 4; ++mt) {
        s16x8 af = *reinterpret_cast<const s16x8*>(sh + (mt * 16 + l15) * 520 + kk * 64 + lgrp * 16);
        acc2[mt] = __builtin_amdgcn_mfma_f32_16x16x32_bf16(af, bD[kk & 1], acc2[mt], 0, 0, 0);
      }
    }
  }

  // ---- epilogue2: bias+ReLU, per-mt stats ----
  {
    float b2v = b2[w * 16 + l15];
    #pragma unroll
    for (int mt = 0; mt < 4; ++mt) {
      float sr[4], qr[4];
      #pragma unroll
      for (int r = 0; r < 4; ++r) {
        float x = fmaxf(acc2[mt][r] + b2v, 0.f);
        acc2[mt][r] = x;
        sr[r] = x; qr[r] = x * x;
      }
      #pragma unroll
      for (int m = 1; m < 16; m <<= 1)
        #pragma unroll
        for (int r = 0; r < 4; ++r) {
          sr[r] += __shfl_xor(sr[r], m);
          qr[r] += __shfl_xor(qr[r], m);
        }
      if (l15 == 0) {
        #pragma unroll
        for (int r = 0; r < 4; ++r) {
          int row = mt * 16 + lgrp * 4 + r;
          st[0][w][row] = sr[r]; st[1][w][row] = qr[r];
        }
      }
    }
  }
  __syncthreads();
  if (tid < 64) {
    float ms = 0.f, mq = 0.f;
    #pragma unroll
    for (int w2 = 0; w2 < 8; ++w2) { ms += st[0][w2][tid]; mq += st[1][w2][tid]; }
    float mu = ms * (1.f / 128.f);
    float var = mq * (1.f / 128.f) - mu * mu;
    murs[0][tid] = mu; murs[1][tid] = rsqrtf(var + LN_EPS);
  }
  __syncthreads();
  // normalize slice -> H2 (264B rows, overlays A/H1; all H1 reads done)
  {
    float g2v = g2[w * 16 + l15], be2v = be2[w * 16 + l15];
    #pragma unroll
    for (int mt = 0; mt < 4; ++mt)
      #pragma unroll
      for (int r = 0; r < 4; ++r) {
        int row = mt * 16 + lgrp * 4 + r;
        float mu = murs[0][row], rs = murs[1][row];
        float y = (acc2[mt][r] - mu) * rs * g2v + be2v;
        *reinterpret_cast<unsigned short*>(sh + row * 264 + (w * 16 + l15) * 2) = f2bf(y);
      }
  }
  __syncthreads();

  // ---- GEMM3: all 64 rows x 16-col slice ----
  f32x4 acc3[4];
  #pragma unroll
  for (int mt = 0; mt < 4; ++mt) acc3[mt] = (f32x4){0.f, 0.f, 0.f, 0.f};
  {
    const unsigned short* ws3w = ws + 98304 + w * (4 * 512);
    s16x8 bD[2];
    bD[0] = *reinterpret_cast<const s16x8*>(ws3w + lane * 8);
    #pragma unroll
    for (int kk = 0; kk < 4; ++kk) {
      if (kk < 3)
        bD[(kk + 1) & 1] = *reinterpret_cast<const s16x8*>(ws3w + (kk + 1) * 512 + lane * 8);
      #pragma unroll
      for (int mt = 0; mt < 4; ++mt) {
        s16x8 af = *reinterpret_cast<const s16x8*>(sh + (mt * 16 + l15) * 264 + kk * 64 + lgrp * 16);
        acc3[mt] = __builtin_amdgcn_mfma_f32_16x16x32_bf16(af, bD[kk & 1], acc3[mt], 0, 0, 0);
      }
    }
  }

  // ---- epilogue3: + bm + imp*Wm[128,:], ReLU, store ----
  {
    int col = w * 16 + l15;
    float bmv = bm[col];
    float wlv = reinterpret_cast<const float*>(ws + 114688)[col];
    #pragma unroll
    for (int mt = 0; mt < 4; ++mt)
      #pragma unroll
      for (int r = 0; r < 4; ++r) {
        int row = mt * 16 + lgrp * 4 + r;
        int g = g0 + row;
        if (g < G) {
          float y = acc3[mt][r] + bmv + imp[g] * wlv;
          out[(size_t)g * 128 + col] = fmaxf(y, 0.f);
        }
      }
  }
}

extern "C" void kernel_launch(void* const* d_in, const int* in_sizes, int n_in,
                              void* d_out, int out_size, void* d_ws, size_t ws_size,
                              hipStream_t stream) {
  const float* emb = (const float*)d_in[0];
  const int* eg    = (const int*)d_in[1];
  const float* imp = (const float*)d_in[2];
  const float* W1  = (const float*)d_in[3];
  const float* b1  = (const float*)d_in[4];
  const float* g1  = (const float*)d_in[5];
  const float* be1 = (const float*)d_in[6];
  const float* W2  = (const float*)d_in[7];
  const float* b2  = (const float*)d_in[8];
  const float* g2  = (const float*)d_in[9];
  const float* be2 = (const float*)d_in[10];
  const float* Wm  = (const float*)d_in[11];
  const float* bm  = (const float*)d_in[12];
  unsigned short* ws = (unsigned short*)d_ws;
  float* out = (float*)d_out;
  int G = in_sizes[2];

  prep_weights<<<(114944 + 255) / 256, 256, 0, stream>>>(W1, W2, Wm, ws);
  int nblk = (G + 63) / 64;
  fused_edge_group<<<nblk, 512, 0, stream>>>(emb, eg, imp, b1, g1, be1, b2, g2, be2, bm,
                                             ws, out, G);
}

// Round 7
// 250.387 us; speedup vs baseline: 2.1028x; 1.3464x over previous
//
#include <hip/hip_runtime.h>

typedef __attribute__((ext_vector_type(8))) short s16x8;
typedef __attribute__((ext_vector_type(4))) float f32x4;

#define LN_EPS 1e-5f

__device__ __forceinline__ unsigned short f2bf(float f) {
  unsigned int u = __float_as_uint(f);
  u += 0x7fffu + ((u >> 16) & 1u);
  return (unsigned short)(u >> 16);
}

__device__ __forceinline__ unsigned cvt_pk_bf16(float lo, float hi) {
  unsigned r;
  asm("v_cvt_pk_bf16_f32 %0, %1, %2" : "=v"(r) : "v"(lo), "v"(hi));
  return r;
}

// tanh-approx GELU: max abs err vs exact ~1e-3.
__device__ __forceinline__ float gelu_fast(float x) {
  float x2 = x * x;
  float y = x * (0.7978845608f + 0.03567740814f * x2);
  float t = __expf(-2.0f * fabsf(y));
  float th = (1.0f - t) / (1.0f + t);
  th = copysignf(th, y);
  return 0.5f * x * (1.0f + th);
}

// ws layout (ushort elems), fragment-major, N-sliced per wave w (frag = 64 lanes x 8 bf16 = 1KB):
//   ws1 [0, 65536)      : GEMM1, frag f = (w*8+kk)*2+nf  (w 0..7, kk 0..7, nf 0..1), n = w*32+nf*16+l15
//   ws2 [65536, 98304)  : GEMM2, frag f = w*8+kk,  n = w*16+l15
//   ws3 [98304, 114688) : GEMM3, frag f = w*4+kk (kk 0..3), n = w*16+l15
//   [114688, 114944)    : 128 f32 = Wm[128,:] (importance row)
__global__ void prep_weights(const float* __restrict__ W1, const float* __restrict__ W2,
                             const float* __restrict__ Wm, unsigned short* __restrict__ ws) {
  int i = blockIdx.x * 256 + threadIdx.x;
  if (i < 65536) {
    int f = i >> 9, lane = (i >> 3) & 63, j = i & 7;
    int w = f >> 4, kk = (f >> 1) & 7, nf = f & 1;
    int n = w * 32 + nf * 16 + (lane & 15);
    int k = kk * 32 + (lane >> 4) * 8 + j;
    ws[i] = f2bf(W1[k * 256 + n]);
  } else if (i < 98304) {
    int t = i - 65536;
    int f = t >> 9, lane = (t >> 3) & 63, j = t & 7;
    int w = f >> 3, kk = f & 7;
    int n = w * 16 + (lane & 15);
    int k = kk * 32 + (lane >> 4) * 8 + j;
    ws[i] = f2bf(W2[k * 128 + n]);
  } else if (i < 114688) {
    int t = i - 98304;
    int f = t >> 9, lane = (t >> 3) & 63, j = t & 7;
    int w = f >> 2, kk = f & 3;
    int n = w * 16 + (lane & 15);
    int k = kk * 32 + (lane >> 4) * 8 + j;
    ws[i] = f2bf(Wm[k * 128 + n]);
  } else if (i < 114944) {
    int c = i - 114688;
    reinterpret_cast<float*>(ws + 114688)[c] = Wm[128 * 128 + c];
  }
}

// 8 waves/block, 64 rows/block; waves split N; weights read once per block.
// SWAPPED-OPERAND MFMA: mfma(Wfrag, Xfrag, acc) -> C^T, so each lane owns ONE
// group-row (col = l15) and 4 consecutive output cols (n = lgrp*4+r): LN reduce
// is 2 shfl levels, epilogue writes are packed b64, final store is float4.
__global__ __launch_bounds__(512, 2) void fused_edge_group(
    const float* __restrict__ emb, const int* __restrict__ eg,
    const float* __restrict__ imp,
    const float* __restrict__ b1, const float* __restrict__ g1, const float* __restrict__ be1,
    const float* __restrict__ b2, const float* __restrict__ g2, const float* __restrict__ be2,
    const float* __restrict__ bm,
    const unsigned short* __restrict__ ws,
    float* __restrict__ out, int G) {

  __shared__ __align__(16) char sh[64 * 520];   // A -> H1 (520B rows) -> H2 (264B rows)
  __shared__ float st[2][8][64];                 // cross-wave LN partials
  __shared__ float murs[2][64];                  // mu, rsqrt per row

  const int tid = threadIdx.x;
  const int lane = tid & 63;
  const int w = tid >> 6;        // 0..7
  const int l15 = lane & 15;
  const int lgrp = lane >> 4;    // 0..3
  const int g0 = blockIdx.x * 64;

  // ---- gather: 64 rows x 512B f32 -> bf16 into sh rows of 520B ----
  #pragma unroll
  for (int it = 0; it < 4; ++it) {
    int s = tid + it * 512;          // 0..2047 : 16B bf16 slots of [64][512B payload]
    int row = s >> 5, sc = s & 31;
    int g = g0 + row; if (g >= G) g = G - 1;
    int idx = eg[2 * g + (sc >> 4)];
    const float4* p = reinterpret_cast<const float4*>(emb + (size_t)idx * 128 + (sc & 15) * 8);
    float4 va = p[0], vb = p[1];
    uint4 v;
    v.x = cvt_pk_bf16(va.x, va.y); v.y = cvt_pk_bf16(va.z, va.w);
    v.z = cvt_pk_bf16(vb.x, vb.y); v.w = cvt_pk_bf16(vb.z, vb.w);
    *reinterpret_cast<uint4*>(sh + row * 520 + sc * 16) = v;
  }
  __syncthreads();

  // ---- GEMM1 (swapped): acc[mt][nf] holds (X@W1)^T; lane: row m=mt*16+l15, n=w*32+nf*16+lgrp*4+r
  f32x4 acc[4][2];
  #pragma unroll
  for (int mt = 0; mt < 4; ++mt) {
    acc[mt][0] = (f32x4){0.f, 0.f, 0.f, 0.f};
    acc[mt][1] = (f32x4){0.f, 0.f, 0.f, 0.f};
  }
  {
    const unsigned short* ws1w = ws + w * 8192;
    s16x8 wA[2][2];
    wA[0][0] = *reinterpret_cast<const s16x8*>(ws1w + 0 * 512 + lane * 8);
    wA[0][1] = *reinterpret_cast<const s16x8*>(ws1w + 1 * 512 + lane * 8);
    #pragma unroll
    for (int kk = 0; kk < 8; ++kk) {
      if (kk < 7) {
        wA[(kk + 1) & 1][0] = *reinterpret_cast<const s16x8*>(ws1w + ((kk + 1) * 2 + 0) * 512 + lane * 8);
        wA[(kk + 1) & 1][1] = *reinterpret_cast<const s16x8*>(ws1w + ((kk + 1) * 2 + 1) * 512 + lane * 8);
      }
      #pragma unroll
      for (int mt = 0; mt < 4; ++mt) {
        s16x8 xf = *reinterpret_cast<const s16x8*>(sh + (mt * 16 + l15) * 520 + kk * 64 + lgrp * 16);
        acc[mt][0] = __builtin_amdgcn_mfma_f32_16x16x32_bf16(wA[kk & 1][0], xf, acc[mt][0], 0, 0, 0);
        acc[mt][1] = __builtin_amdgcn_mfma_f32_16x16x32_bf16(wA[kk & 1][1], xf, acc[mt][1], 0, 0, 0);
      }
    }
  }

  // ---- epilogue1: bias+GELU, row-local stats (2 shfl levels) ----
  {
    float4 b1v0 = *reinterpret_cast<const float4*>(b1 + w * 32 + lgrp * 4);
    float4 b1v1 = *reinterpret_cast<const float4*>(b1 + w * 32 + 16 + lgrp * 4);
    #pragma unroll
    for (int mt = 0; mt < 4; ++mt) {
      float s = 0.f, q = 0.f;
      #pragma unroll
      for (int r = 0; r < 4; ++r) {
        float x0 = gelu_fast(acc[mt][0][r] + ((const float*)&b1v0)[r]);
        float x1 = gelu_fast(acc[mt][1][r] + ((const float*)&b1v1)[r]);
        acc[mt][0][r] = x0; acc[mt][1][r] = x1;
        s += x0 + x1; q += x0 * x0 + x1 * x1;
      }
      s += __shfl_xor(s, 16); q += __shfl_xor(q, 16);
      s += __shfl_xor(s, 32); q += __shfl_xor(q, 32);
      if (lane < 16) { st[0][w][mt * 16 + lane] = s; st[1][w][mt * 16 + lane] = q; }
    }
  }
  __syncthreads();
  if (tid < 64) {
    float ms = 0.f, mq = 0.f;
    #pragma unroll
    for (int w2 = 0; w2 < 8; ++w2) { ms += st[0][w2][tid]; mq += st[1][w2][tid]; }
    float mu = ms * (1.f / 256.f);
    float var = mq * (1.f / 256.f) - mu * mu;
    murs[0][tid] = mu; murs[1][tid] = rsqrtf(var + LN_EPS);
  }
  __syncthreads();
  // normalize -> H1 (packed b64 writes; A fully consumed)
  {
    float4 g1v0 = *reinterpret_cast<const float4*>(g1 + w * 32 + lgrp * 4);
    float4 g1v1 = *reinterpret_cast<const float4*>(g1 + w * 32 + 16 + lgrp * 4);
    float4 be1v0 = *reinterpret_cast<const float4*>(be1 + w * 32 + lgrp * 4);
    float4 be1v1 = *reinterpret_cast<const float4*>(be1 + w * 32 + 16 + lgrp * 4);
    #pragma unroll
    for (int mt = 0; mt < 4; ++mt) {
      int row = mt * 16 + l15;
      float mu = murs[0][row], rs = murs[1][row];
      float y[8];
      #pragma unroll
      for (int r = 0; r < 4; ++r) {
        y[r]     = fmaf((acc[mt][0][r] - mu) * rs, ((const float*)&g1v0)[r], ((const float*)&be1v0)[r]);
        y[4 + r] = fmaf((acc[mt][1][r] - mu) * rs, ((const float*)&g1v1)[r], ((const float*)&be1v1)[r]);
      }
      uint2 p0, p1;
      p0.x = cvt_pk_bf16(y[0], y[1]); p0.y = cvt_pk_bf16(y[2], y[3]);
      p1.x = cvt_pk_bf16(y[4], y[5]); p1.y = cvt_pk_bf16(y[6], y[7]);
      char* rp = sh + row * 520 + (w * 32 + lgrp * 4) * 2;
      *reinterpret_cast<uint2*>(rp) = p0;
      *reinterpret_cast<uint2*>(rp + 32) = p1;
    }
  }
  __syncthreads();

  // ---- GEMM2 (swapped): acc2[mt]; lane: row m, n2 = w*16+lgrp*4+r ----
  f32x4 acc2[4];
  #pragma unroll
  for (int mt = 0; mt < 4; ++mt) acc2[mt] = (f32x4){0.f, 0.f, 0.f, 0.f};
  {
    const unsigned short* ws2w = ws + 65536 + w * 4096;
    s16x8 wA[2];
    wA[0] = *reinterpret_cast<const s16x8*>(ws2w + lane * 8);
    #pragma unroll
    for (int kk = 0; kk < 8; ++kk) {
      if (kk < 7)
        wA[(kk + 1) & 1] = *reinterpret_cast<const s16x8*>(ws2w + (kk + 1) * 512 + lane * 8);
      #pragma unroll
      for (int mt = 0; mt < 4; ++mt) {
        s16x8 xf = *reinterpret_cast<const s16x8*>(sh + (mt * 16 + l15) * 520 + kk * 64 + lgrp * 16);
        acc2[mt] = __builtin_amdgcn_mfma_f32_16x16x32_bf16(wA[kk & 1], xf, acc2[mt], 0, 0, 0);
      }
    }
  }

  // ---- epilogue2: bias+ReLU, stats ----
  {
    float4 b2v = *reinterpret_cast<const float4*>(b2 + w * 16 + lgrp * 4);
    #pragma unroll
    for (int mt = 0; mt < 4; ++mt) {
      float s = 0.f, q = 0.f;
      #pragma unroll
      for (int r = 0; r < 4; ++r) {
        float x = fmaxf(acc2[mt][r] + ((const float*)&b2v)[r], 0.f);
        acc2[mt][r] = x;
        s += x; q += x * x;
      }
      s += __shfl_xor(s, 16); q += __shfl_xor(q, 16);
      s += __shfl_xor(s, 32); q += __shfl_xor(q, 32);
      if (lane < 16) { st[0][w][mt * 16 + lane] = s; st[1][w][mt * 16 + lane] = q; }
    }
  }
  __syncthreads();
  if (tid < 64) {
    float ms = 0.f, mq = 0.f;
    #pragma unroll
    for (int w2 = 0; w2 < 8; ++w2) { ms += st[0][w2][tid]; mq += st[1][w2][tid]; }
    float mu = ms * (1.f / 128.f);
    float var = mq * (1.f / 128.f) - mu * mu;
    murs[0][tid] = mu; murs[1][tid] = rsqrtf(var + LN_EPS);
  }
  __syncthreads();
  // normalize -> H2 (264B rows, overlays A/H1; all H1 reads done)
  {
    float4 g2v = *reinterpret_cast<const float4*>(g2 + w * 16 + lgrp * 4);
    float4 be2v = *reinterpret_cast<const float4*>(be2 + w * 16 + lgrp * 4);
    #pragma unroll
    for (int mt = 0; mt < 4; ++mt) {
      int row = mt * 16 + l15;
      float mu = murs[0][row], rs = murs[1][row];
      float y[4];
      #pragma unroll
      for (int r = 0; r < 4; ++r)
        y[r] = fmaf((acc2[mt][r] - mu) * rs, ((const float*)&g2v)[r], ((const float*)&be2v)[r]);
      uint2 p;
      p.x = cvt_pk_bf16(y[0], y[1]); p.y = cvt_pk_bf16(y[2], y[3]);
      *reinterpret_cast<uint2*>(sh + row * 264 + (w * 16 + lgrp * 4) * 2) = p;
    }
  }
  __syncthreads();

  // ---- GEMM3 (swapped) ----
  f32x4 acc3[4];
  #pragma unroll
  for (int mt = 0; mt < 4; ++mt) acc3[mt] = (f32x4){0.f, 0.f, 0.f, 0.f};
  {
    const unsigned short* ws3w = ws + 98304 + w * 2048;
    s16x8 wA[2];
    wA[0] = *reinterpret_cast<const s16x8*>(ws3w + lane * 8);
    #pragma unroll
    for (int kk = 0; kk < 4; ++kk) {
      if (kk < 3)
        wA[(kk + 1) & 1] = *reinterpret_cast<const s16x8*>(ws3w + (kk + 1) * 512 + lane * 8);
      #pragma unroll
      for (int mt = 0; mt < 4; ++mt) {
        s16x8 xf = *reinterpret_cast<const s16x8*>(sh + (mt * 16 + l15) * 264 + kk * 64 + lgrp * 16);
        acc3[mt] = __builtin_amdgcn_mfma_f32_16x16x32_bf16(wA[kk & 1], xf, acc3[mt], 0, 0, 0);
      }
    }
  }

  // ---- epilogue3: + bm + imp*Wm[128,:], ReLU, float4 store ----
  {
    int col0 = w * 16 + lgrp * 4;
    float4 bmv = *reinterpret_cast<const float4*>(bm + col0);
    float4 wlv = *reinterpret_cast<const float4*>(reinterpret_cast<const float*>(ws + 114688) + col0);
    #pragma unroll
    for (int mt = 0; mt < 4; ++mt) {
      int g = g0 + mt * 16 + l15;
      float impv = imp[g < G ? g : (G - 1)];
      float4 y;
      y.x = fmaxf(acc3[mt][0] + bmv.x + impv * wlv.x, 0.f);
      y.y = fmaxf(acc3[mt][1] + bmv.y + impv * wlv.y, 0.f);
      y.z = fmaxf(acc3[mt][2] + bmv.z + impv * wlv.z, 0.f);
      y.w = fmaxf(acc3[mt][3] + bmv.w + impv * wlv.w, 0.f);
      if (g < G)
        *reinterpret_cast<float4*>(out + (size_t)g * 128 + col0) = y;
    }
  }
}

extern "C" void kernel_launch(void* const* d_in, const int* in_sizes, int n_in,
                              void* d_out, int out_size, void* d_ws, size_t ws_size,
                              hipStream_t stream) {
  const float* emb = (const float*)d_in[0];
  const int* eg    = (const int*)d_in[1];
  const float* imp = (const float*)d_in[2];
  const float* W1  = (const float*)d_in[3];
  const float* b1  = (const float*)d_in[4];
  const float* g1  = (const float*)d_in[5];
  const float* be1 = (const float*)d_in[6];
  const float* W2  = (const float*)d_in[7];
  const float* b2  = (const float*)d_in[8];
  const float* g2  = (const float*)d_in[9];
  const float* be2 = (const float*)d_in[10];
  const float* Wm  = (const float*)d_in[11];
  const float* bm  = (const float*)d_in[12];
  unsigned short* ws = (unsigned short*)d_ws;
  float* out = (float*)d_out;
  int G = in_sizes[2];

  prep_weights<<<(114944 + 255) / 256, 256, 0, stream>>>(W1, W2, Wm, ws);
  int nblk = (G + 63) / 64;
  fused_edge_group<<<nblk, 512, 0, stream>>>(emb, eg, imp, b1, g1, be1, b2, g2, be2, bm,
                                             ws, out, G);
}